// Round 5
// baseline (516.153 us; speedup 1.0000x reference)
//
#include <hip/hip_runtime.h>
#include <math.h>

#define NN 40000
#define NE 600000
#define NG 64
#define DIM_IN 128
#define HH 128
#define HH2 256

using half8 = __attribute__((ext_vector_type(8))) _Float16;
using half4 = __attribute__((ext_vector_type(4))) _Float16;
using h2    = __attribute__((ext_vector_type(2))) _Float16;
using f4    = __attribute__((ext_vector_type(4))) float;

__device__ __forceinline__ int lower_bound_dev(const int* a, int n, int key) {
    int lo = 0, hi = n;
    while (lo < hi) { int mid = (lo + hi) >> 1; if (a[mid] < key) lo = mid + 1; else hi = mid; }
    return lo;
}

// ------- convert (x->fp16, weights->fp16 B^T) + pooled zero + count_rank, one kernel -------
#define NX (NN*DIM_IN)
#define NX4 (NX/4)
__global__ void convert_kernel(const float* __restrict__ x, const float* __restrict__ node_w,
                               const float* __restrict__ lin1_w, const float* __restrict__ lin2_w,
                               const int* __restrict__ dst, int* __restrict__ counts,
                               int* __restrict__ rank, float* __restrict__ pooled,
                               _Float16* __restrict__ xh, _Float16* __restrict__ nwt,
                               _Float16* __restrict__ w1t, _Float16* __restrict__ w2t)
{
    int id = blockIdx.x * blockDim.x + threadIdx.x;
    if (id < NX4) {
        float4 v = *(const float4*)(x + (size_t)id * 4);
        half4 o; o.x = (_Float16)v.x; o.y = (_Float16)v.y; o.z = (_Float16)v.z; o.w = (_Float16)v.w;
        *(half4*)(xh + (size_t)id * 4) = o;
        return;
    }
    id -= NX4;
    if (id < 16384) { int n = id >> 7, k = id & 127; nwt[id] = (_Float16)node_w[k*128 + n]; return; }
    id -= 16384;
    if (id < 98304) {
        int l = id >> 15, r = id & 32767;
        int n = r >> 7, k = r & 127;
        w1t[id] = (_Float16)lin1_w[l*32768 + k*256 + n];
        return;
    }
    id -= 98304;
    if (id < 98304) {
        int l = id >> 15, r = id & 32767;
        int n = r >> 8, k = r & 255;
        w2t[id] = (_Float16)lin2_w[l*32768 + k*128 + n];
        return;
    }
    id -= 98304;
    if (id < NG * HH) { pooled[id] = 0.f; return; }
    id -= NG * HH;
    if (id < NE) rank[id] = atomicAdd(&counts[dst[id]], 1);   // counts memset'd before this kernel
}

// ---------------- CSR scan (rowp from counts) ----------------
__global__ __launch_bounds__(1024) void scanA_kernel(const int* __restrict__ counts,
                                                     int* __restrict__ tmp, int* __restrict__ btot) {
    __shared__ int wpre[16];
    int t = threadIdx.x, lane = t & 63, wid = t >> 6;
    int i = blockIdx.x * 1024 + t;
    int v = (i < NN) ? counts[i] : 0;
    int s = v;
    #pragma unroll
    for (int off = 1; off < 64; off <<= 1) {
        int u = __shfl_up(s, off, 64);
        if (lane >= off) s += u;
    }
    if (lane == 63) wpre[wid] = s;
    __syncthreads();
    if (t == 0) {
        int run = 0;
        #pragma unroll
        for (int j = 0; j < 16; ++j) { int xv = wpre[j]; wpre[j] = run; run += xv; }
        btot[blockIdx.x] = run;
    }
    __syncthreads();
    if (i < NN) tmp[i] = s + wpre[wid];
}

__global__ __launch_bounds__(1024) void scanC_kernel(const int* __restrict__ tmp,
                                                     const int* __restrict__ btot,
                                                     int* __restrict__ rowp) {
    __shared__ int s_off;
    int t = threadIdx.x;
    if (t < 64) {
        int v = (t < blockIdx.x) ? btot[t] : 0;    // sum of preceding block totals
        #pragma unroll
        for (int o = 32; o > 0; o >>= 1) v += __shfl_down(v, o, 64);
        if (t == 0) s_off = v;
    }
    __syncthreads();
    int i = blockIdx.x * 1024 + t;
    if (i < NN) rowp[i + 1] = tmp[i] + s_off;
    if (i == 0) rowp[0] = 0;
}

__global__ void fill2_kernel(const int* __restrict__ src, const int* __restrict__ dst,
                             const float* __restrict__ eattr, const int* __restrict__ rowp,
                             const int* __restrict__ rank, int2* __restrict__ rec) {
    int e = blockIdx.x * blockDim.x + threadIdx.x;
    if (e < NE) {
        int pos = rowp[dst[e]] + rank[e];
        rec[pos] = make_int2(src[e], __float_as_int(eattr[e]));
    }
}

// ------------- fp16 MFMA GEMM (node linear): C half = A @ Bt^T + bias -------------
__global__ __launch_bounds__(256) void gemm_mfma(
    const _Float16* __restrict__ A, const _Float16* __restrict__ Bt,
    const float* __restrict__ bias, _Float16* __restrict__ C,
    int M, int N, int K)
{
    constexpr int LDA = 40;
    __shared__ _Float16 As[64 * LDA];
    __shared__ _Float16 Bs[128 * LDA];
    int t = threadIdx.x;
    int row0 = blockIdx.y * 64;
    int col0 = blockIdx.x * 128;
    int w = t >> 6, lane = t & 63;
    int wm = w & 1, wn = w >> 1;
    int q = lane >> 4, l16 = lane & 15;
    f4 acc[2][4];
    #pragma unroll
    for (int i = 0; i < 2; ++i)
        #pragma unroll
        for (int j = 0; j < 4; ++j)
            acc[i][j] = (f4){0.f, 0.f, 0.f, 0.f};

    for (int k0 = 0; k0 < K; k0 += 32) {
        {
            int r = t >> 2, seg = t & 3;
            *(float4*)&As[r * LDA + seg * 8] =
                *(const float4*)(A + (size_t)(row0 + r) * K + k0 + seg * 8);
        }
        #pragma unroll
        for (int i = 0; i < 2; ++i) {
            int idx = t + i * 256;
            int r = idx >> 2, seg = idx & 3;
            *(float4*)&Bs[r * LDA + seg * 8] =
                *(const float4*)(Bt + (size_t)(col0 + r) * K + k0 + seg * 8);
        }
        __syncthreads();
        half8 af[2], bf[4];
        #pragma unroll
        for (int i = 0; i < 2; ++i)
            af[i] = *(const half8*)&As[(wm * 32 + i * 16 + l16) * LDA + q * 8];
        #pragma unroll
        for (int j = 0; j < 4; ++j)
            bf[j] = *(const half8*)&Bs[(wn * 64 + j * 16 + l16) * LDA + q * 8];
        #pragma unroll
        for (int i = 0; i < 2; ++i)
            #pragma unroll
            for (int j = 0; j < 4; ++j)
                acc[i][j] = __builtin_amdgcn_mfma_f32_16x16x32_f16(af[i], bf[j], acc[i][j], 0, 0, 0);
        __syncthreads();
    }
    #pragma unroll
    for (int j = 0; j < 4; ++j) {
        int col = col0 + wn * 64 + j * 16 + l16;
        float bv = bias[col];
        #pragma unroll
        for (int i = 0; i < 2; ++i) {
            int rbase = row0 + wm * 32 + i * 16 + q * 4;
            #pragma unroll
            for (int rg = 0; rg < 4; ++rg)
                C[(size_t)(rbase + rg) * N + col] = (_Float16)(acc[i][j][rg] + bv);
        }
    }
}

// ============ fused layer: agg (streamed) -> lin1 -> LN1 -> ReLU -> lin2 [+res] -> h;
//              blockLN -> ReLU -> xout.  64 rows/block, 256 threads. ============
template<int RES>
__global__ __launch_bounds__(256) void layer_fused(
    const _Float16* __restrict__ xh,     // prev activations (gather source + roots)
    const int* __restrict__ rowp,
    const int2* __restrict__ rec,
    const float* __restrict__ ew, const float* __restrict__ eb,
    const float* __restrict__ tptr, int layer,
    const _Float16* __restrict__ w1t, const float* __restrict__ b1,
    const float* __restrict__ g1, const float* __restrict__ bt1,
    const _Float16* __restrict__ w2t, const float* __restrict__ b2,
    float* __restrict__ h,
    const float* __restrict__ bg, const float* __restrict__ bb,
    _Float16* __restrict__ xout)
{
    constexpr int LDA = 136;     // As row stride (halves), 272B = 17x16B
    constexpr int LDB = 40;
    // LDS: [0,32768) midh (swizzled, unions As) | [32768,53248) Bs | stats
    __shared__ __align__(16) char smem[54272];
    _Float16* As   = (_Float16*)smem;
    _Float16* midh = (_Float16*)smem;
    _Float16* Bs   = (_Float16*)(smem + 32768);
    float* ssum    = (float*)(smem + 53248);   // [64][2]
    float* ssum2   = (float*)(smem + 53760);   // [64][2]

    int t = threadIdx.x;
    int row0 = blockIdx.x * 64;
    int w = t >> 6, lane = t & 63;
    int wm = w & 1, wn = w >> 1;
    int q = lane >> 4, l16 = lane & 15;
    int c0 = 2 * lane;

    // ---------------- aggregation: wave w streams edges of its 16 nodes ----------------
    {
        int d0 = row0 + w * 16;
        float tc = tptr[layer];
        float ew0 = ew[c0], eb0 = eb[c0];
        float ew1 = ew[c0 + 1], eb1 = eb[c0 + 1];
        #pragma unroll
        for (int i = 0; i < 16; ++i) {          // pre-store roots into As
            h2 rt = *(const h2*)(xh + ((size_t)(d0 + i) << 7) + c0);
            *(h2*)&As[(w * 16 + i) * LDA + c0] = rt;
        }
        int rp_l = rowp[d0 + min(lane, 16)];
        int beg = __shfl(rp_l, 0, 64);
        int end = __shfl(rp_l, 16, 64);
        int total = end - beg;
        int cur = 0;
        int nb_rel = __shfl(rp_l, 1, 64) - beg;
        float den0 = 0.f, num0 = 0.f, den1 = 0.f, num1 = 0.f;

        auto finalize = [&]() {
            float o0 = num0 / fmaxf(den0, 1e-16f);
            float o1 = num1 / fmaxf(den1, 1e-16f);
            h2* slot = (h2*)&As[(w * 16 + cur) * LDA + c0];
            h2 old = *slot;
            h2 nv; nv.x = (_Float16)((float)old.x + o0); nv.y = (_Float16)((float)old.y + o1);
            *slot = nv;
            den0 = num0 = den1 = num1 = 0.f;
            cur++;
            nb_rel = __shfl(rp_l, min(cur + 1, 16), 64) - beg;
        };

        if (total > 0) {
            int ms = 0; float ma = 0.f;            // current 64-edge meta chunk
            auto load_chunk = [&](int ci) {
                int jj = min(ci * 64 + lane, total - 1);
                int2 mv = rec[beg + jj];
                ms = mv.x; ma = __int_as_float(mv.y);
            };
            h2 gA[16], gB[16]; float aA[16], aB[16];
            auto issue = [&](h2* g, float* aa, int g0) {
                #pragma unroll
                for (int u = 0; u < 16; ++u) {
                    int jl = min(g0 + u, total - 1) & 63;   // groups never cross chunks
                    int s = __shfl(ms, jl, 64);
                    aa[u] = __shfl(ma, jl, 64);
                    g[u] = *(const h2*)(xh + ((size_t)s << 7) + c0);
                }
            };
            auto consume = [&](h2* g, float* aa, int g0) {
                #pragma unroll
                for (int u = 0; u < 16; ++u) {
                    int p = g0 + u;
                    if (p < total) {                        // wave-uniform
                        while (cur < 16 && p == nb_rel) finalize();
                        float m0 = fmaxf(__fmaf_rn(aa[u], ew0, eb0) + (float)g[u].x, 0.f) + 1e-7f;
                        float m1 = fmaxf(__fmaf_rn(aa[u], ew1, eb1) + (float)g[u].y, 0.f) + 1e-7f;
                        float e0 = __expf(m0 * tc), e1 = __expf(m1 * tc);
                        den0 += e0; num0 = __fmaf_rn(e0, m0, num0);
                        den1 += e1; num1 = __fmaf_rn(e1, m1, num1);
                    }
                }
            };
            load_chunk(0);
            issue(gA, aA, 0);
            int ng = (total + 15) >> 4;
            for (int gi = 0; gi < ng; ++gi) {
                int gn = gi + 1;
                if (gn < ng) {
                    if ((gn & 3) == 0) load_chunk(gn >> 2);
                    if (gi & 1) issue(gA, aA, gn << 4);
                    else        issue(gB, aB, gn << 4);
                }
                if (gi & 1) consume(gB, aB, gi << 4);
                else        consume(gA, aA, gi << 4);
            }
        }
        while (cur < 16) finalize();
    }
    // (first __syncthreads inside lin1 loop covers agg completion)

    // ---------------- lin1: mid[64][256] = As @ w1t^T ----------------
    f4 acc[2][8];
    #pragma unroll
    for (int i = 0; i < 2; ++i)
        #pragma unroll
        for (int j = 0; j < 8; ++j)
            acc[i][j] = (f4){0.f, 0.f, 0.f, 0.f};
    for (int k0 = 0; k0 < 128; k0 += 32) {
        #pragma unroll
        for (int p = 0; p < 4; ++p) {           // stage B1 tile [256][32]
            int idx = t + p * 256;
            int r = idx >> 2, seg = idx & 3;
            *(float4*)&Bs[r * LDB + seg * 8] =
                *(const float4*)(w1t + (size_t)r * 128 + k0 + seg * 8);
        }
        __syncthreads();
        half8 af[2], bf[8];
        #pragma unroll
        for (int i = 0; i < 2; ++i)
            af[i] = *(const half8*)&As[(wm * 32 + i * 16 + l16) * LDA + k0 + q * 8];
        #pragma unroll
        for (int j = 0; j < 8; ++j)
            bf[j] = *(const half8*)&Bs[(wn * 128 + j * 16 + l16) * LDB + q * 8];
        #pragma unroll
        for (int i = 0; i < 2; ++i)
            #pragma unroll
            for (int j = 0; j < 8; ++j)
                acc[i][j] = __builtin_amdgcn_mfma_f32_16x16x32_f16(af[i], bf[j], acc[i][j], 0, 0, 0);
        __syncthreads();
    }

    // ---------------- bias + LN1 stats ----------------
    float b1v[8], g1v[8], bt1v[8];
    #pragma unroll
    for (int j = 0; j < 8; ++j) {
        int col = wn * 128 + j * 16 + l16;
        b1v[j] = b1[col]; g1v[j] = g1[col]; bt1v[j] = bt1[col];
    }
    float vals[2][8][4];
    #pragma unroll
    for (int i = 0; i < 2; ++i)
        #pragma unroll
        for (int j = 0; j < 8; ++j)
            #pragma unroll
            for (int rg = 0; rg < 4; ++rg)
                vals[i][j][rg] = acc[i][j][rg] + b1v[j];
    #pragma unroll
    for (int i = 0; i < 2; ++i) {
        #pragma unroll
        for (int rg = 0; rg < 4; ++rg) {
            float ps = 0.f, ps2 = 0.f;
            #pragma unroll
            for (int j = 0; j < 8; ++j) { float v = vals[i][j][rg]; ps += v; ps2 += v * v; }
            #pragma unroll
            for (int off = 1; off < 16; off <<= 1) {
                ps  += __shfl_xor(ps,  off, 16);
                ps2 += __shfl_xor(ps2, off, 16);
            }
            if (l16 == 0) {
                int row = wm * 32 + i * 16 + q * 4 + rg;
                ssum[row * 2 + wn] = ps; ssum2[row * 2 + wn] = ps2;
            }
        }
    }
    __syncthreads();   // also separates last As read from midh writes (union)
    #pragma unroll
    for (int i = 0; i < 2; ++i) {
        #pragma unroll
        for (int rg = 0; rg < 4; ++rg) {
            int row = wm * 32 + i * 16 + q * 4 + rg;
            float S = ssum[row * 2 + 0] + ssum[row * 2 + 1];
            float S2 = ssum2[row * 2 + 0] + ssum2[row * 2 + 1];
            float mu = S * (1.0f / 256.0f);
            float var = S2 * (1.0f / 256.0f) - mu * mu;
            float rstd = rsqrtf(var + 1e-5f);
            #pragma unroll
            for (int j = 0; j < 8; ++j) {
                int col = wn * 128 + j * 16 + l16;
                float o = fmaxf((vals[i][j][rg] - mu) * rstd * g1v[j] + bt1v[j], 0.f);
                int pg = (col >> 3) ^ (row & 31);          // XOR-swizzled midh
                midh[row * 256 + (pg << 3) + (col & 7)] = (_Float16)o;
            }
        }
    }
    __syncthreads();

    // ---------------- lin2: out[64][128] = mid @ w2t^T ----------------
    f4 acc2[2][4];
    #pragma unroll
    for (int i = 0; i < 2; ++i)
        #pragma unroll
        for (int j = 0; j < 4; ++j)
            acc2[i][j] = (f4){0.f, 0.f, 0.f, 0.f};
    for (int k0 = 0; k0 < 256; k0 += 32) {
        #pragma unroll
        for (int p = 0; p < 2; ++p) {           // stage B2 tile [128][32]
            int idx = t + p * 256;
            int r = idx >> 2, seg = idx & 3;
            *(float4*)&Bs[r * LDB + seg * 8] =
                *(const float4*)(w2t + (size_t)r * 256 + k0 + seg * 8);
        }
        __syncthreads();
        half8 af2[2], bf2[4];
        #pragma unroll
        for (int i = 0; i < 2; ++i) {
            int rr = wm * 32 + i * 16 + l16;
            int pg = ((k0 >> 3) + q) ^ (rr & 31);
            af2[i] = *(const half8*)&midh[rr * 256 + (pg << 3)];
        }
        #pragma unroll
        for (int j = 0; j < 4; ++j)
            bf2[j] = *(const half8*)&Bs[(wn * 64 + j * 16 + l16) * LDB + q * 8];
        #pragma unroll
        for (int i = 0; i < 2; ++i)
            #pragma unroll
            for (int j = 0; j < 4; ++j)
                acc2[i][j] = __builtin_amdgcn_mfma_f32_16x16x32_f16(af2[i], bf2[j], acc2[i][j], 0, 0, 0);
        __syncthreads();
    }

    // ---------------- epilogue: bias (+res) -> h; block LN + ReLU -> xout ----------------
    float b2v[4], bgv[4], bbv[4];
    #pragma unroll
    for (int j = 0; j < 4; ++j) {
        int col = wn * 64 + j * 16 + l16;
        b2v[j] = b2[col]; bgv[j] = bg[col]; bbv[j] = bb[col];
    }
    float ov[2][4][4];
    #pragma unroll
    for (int i = 0; i < 2; ++i) {
        #pragma unroll
        for (int rg = 0; rg < 4; ++rg) {
            int row = wm * 32 + i * 16 + q * 4 + rg;
            #pragma unroll
            for (int j = 0; j < 4; ++j) {
                int col = wn * 64 + j * 16 + l16;
                float v = acc2[i][j][rg] + b2v[j];
                size_t gidx = (size_t)(row0 + row) * 128 + col;
                if (RES) v += h[gidx];
                h[gidx] = v;
                ov[i][j][rg] = v;
            }
        }
    }
    #pragma unroll
    for (int i = 0; i < 2; ++i) {
        #pragma unroll
        for (int rg = 0; rg < 4; ++rg) {
            float ps = 0.f, ps2 = 0.f;
            #pragma unroll
            for (int j = 0; j < 4; ++j) { float v = ov[i][j][rg]; ps += v; ps2 += v * v; }
            #pragma unroll
            for (int off = 1; off < 16; off <<= 1) {
                ps  += __shfl_xor(ps,  off, 16);
                ps2 += __shfl_xor(ps2, off, 16);
            }
            if (l16 == 0) {
                int row = wm * 32 + i * 16 + q * 4 + rg;
                ssum[row * 2 + wn] = ps; ssum2[row * 2 + wn] = ps2;
            }
        }
    }
    __syncthreads();
    #pragma unroll
    for (int i = 0; i < 2; ++i) {
        #pragma unroll
        for (int rg = 0; rg < 4; ++rg) {
            int row = wm * 32 + i * 16 + q * 4 + rg;
            float S = ssum[row * 2 + 0] + ssum[row * 2 + 1];
            float S2 = ssum2[row * 2 + 0] + ssum2[row * 2 + 1];
            float mu = S * (1.0f / 128.0f);
            float var = S2 * (1.0f / 128.0f) - mu * mu;
            float rstd = rsqrtf(var + 1e-5f);
            #pragma unroll
            for (int j = 0; j < 4; ++j) {
                int col = wn * 64 + j * 16 + l16;
                float o = fmaxf((ov[i][j][rg] - mu) * rstd * bgv[j] + bbv[j], 0.f);
                xout[(size_t)(row0 + row) * 128 + col] = (_Float16)o;
            }
        }
    }
}

// ------------- mean pool over sorted batch (half input) -------------
__global__ __launch_bounds__(128) void pool_kernel(
    const _Float16* __restrict__ f, const int* __restrict__ batch, float* __restrict__ pooled)
{
    int g = blockIdx.x;
    int chunk = blockIdx.y;
    int c = threadIdx.x;
    int s = lower_bound_dev(batch, NN, g);
    int e = lower_bound_dev(batch, NN, g + 1);
    int len = e - s;
    if (len <= 0) return;
    int nch = gridDim.y;
    int per = (len + nch - 1) / nch;
    int cs = s + chunk * per;
    int ce = min(cs + per, e);
    if (cs >= ce) return;
    float acc = 0.f;
    for (int n = cs; n < ce; ++n) acc += (float)f[(size_t)n * HH + c];
    atomicAdd(&pooled[g * HH + c], acc);
}

// ------------- MLP head -------------
__global__ __launch_bounds__(128) void head_kernel(
    const float* __restrict__ pooled, const int* __restrict__ batch,
    const float* __restrict__ hw1, const float* __restrict__ hb1,
    const float* __restrict__ hw2, const float* __restrict__ hb2,
    const float* __restrict__ hw3, const float* __restrict__ hb3,
    float* __restrict__ out)
{
    __shared__ float p[HH];
    __shared__ float o1[64];
    __shared__ float o2[32];
    int g = blockIdx.x;
    int t = threadIdx.x;
    int s = lower_bound_dev(batch, NN, g);
    int e = lower_bound_dev(batch, NN, g + 1);
    float cnt = fmaxf((float)(e - s), 1.0f);
    p[t] = pooled[g * HH + t] / cnt;
    __syncthreads();
    if (t < 64) {
        float acc = hb1[t];
        for (int k = 0; k < HH; ++k) acc += p[k] * hw1[k * 64 + t];
        o1[t] = fmaxf(acc, 0.f);
    }
    __syncthreads();
    if (t < 32) {
        float acc = hb2[t];
        for (int k = 0; k < 64; ++k) acc += o1[k] * hw2[k * 32 + t];
        o2[t] = fmaxf(acc, 0.f);
    }
    __syncthreads();
    if (t == 0) {
        float acc = hb3[0];
        for (int k = 0; k < 32; ++k) acc += o2[k] * hw3[k];
        out[g] = acc;
    }
}

extern "C" void kernel_launch(void* const* d_in, const int* in_sizes, int n_in,
                              void* d_out, int out_size, void* d_ws, size_t ws_size,
                              hipStream_t stream)
{
    const float* x      = (const float*)d_in[0];
    const float* eattr  = (const float*)d_in[1];
    const float* node_w = (const float*)d_in[2];
    const float* node_b = (const float*)d_in[3];
    const float* edge_w = (const float*)d_in[4];
    const float* edge_b = (const float*)d_in[5];
    const float* tptr   = (const float*)d_in[6];
    const float* lin1_w = (const float*)d_in[7];
    const float* lin1_b = (const float*)d_in[8];
    const float* ln1_g  = (const float*)d_in[9];
    const float* ln1_bt = (const float*)d_in[10];
    const float* lin2_w = (const float*)d_in[11];
    const float* lin2_b = (const float*)d_in[12];
    const float* blk_g  = (const float*)d_in[13];
    const float* blk_b  = (const float*)d_in[14];
    const float* hw1    = (const float*)d_in[15];
    const float* hb1    = (const float*)d_in[16];
    const float* hw2    = (const float*)d_in[17];
    const float* hb2    = (const float*)d_in[18];
    const float* hw3    = (const float*)d_in[19];
    const float* hb3    = (const float*)d_in[20];
    const int*   eidx   = (const int*)d_in[21];
    const int*   batch  = (const int*)d_in[22];
    const int* src = eidx;
    const int* dst = eidx + NE;
    float* out = (float*)d_out;

    char* ws = (char*)d_ws;
    size_t off = 0;
    auto carve = [&](size_t bytes) -> char* {
        char* p = ws + off;
        off = (off + bytes + 255) & ~(size_t)255;
        return p;
    };
    float*    h      = (float*)carve((size_t)NN * HH * 4);
    _Float16* xh_in  = (_Float16*)carve((size_t)NX * 2);
    _Float16* xa     = (_Float16*)carve((size_t)NN * HH * 2);
    _Float16* xb     = (_Float16*)carve((size_t)NN * HH * 2);
    _Float16* rh     = (_Float16*)carve((size_t)NN * HH * 2);
    _Float16* nwt    = (_Float16*)carve((size_t)16384 * 2);
    _Float16* w1t    = (_Float16*)carve((size_t)98304 * 2);
    _Float16* w2t    = (_Float16*)carve((size_t)98304 * 2);
    int*      counts = (int*)carve((size_t)NN * 4);
    int*      rank   = (int*)carve((size_t)NE * 4);
    int*      tmp    = (int*)carve((size_t)NN * 4);
    int*      btot   = (int*)carve((size_t)64 * 4);
    int*      rowp   = (int*)carve((size_t)(NN + 1) * 4);
    int2*     rec    = (int2*)carve((size_t)NE * 8);
    float*    pooled = (float*)carve((size_t)NG * HH * 4);

    hipMemsetAsync(counts, 0, (size_t)NN * 4, stream);

    {   // convert + pooled-zero + count_rank
        int total = NX4 + 16384 + 98304 + 98304 + NG * HH + NE;
        convert_kernel<<<(total + 255) / 256, 256, 0, stream>>>(
            x, node_w, lin1_w, lin2_w, dst, counts, rank, pooled, xh_in, nwt, w1t, w2t);
    }
    const int NB = (NN + 1023) / 1024;   // 40
    scanA_kernel<<<NB, 1024, 0, stream>>>(counts, tmp, btot);
    scanC_kernel<<<NB, 1024, 0, stream>>>(tmp, btot, rowp);
    fill2_kernel<<<(NE + 255) / 256, 256, 0, stream>>>(src, dst, eattr, rowp, rank, rec);

    // node linear: xa = half(x @ node_w + node_b)
    gemm_mfma<<<dim3(1, NN / 64), 256, 0, stream>>>(xh_in, nwt, node_b, xa, NN, HH, DIM_IN);

    // layer 0: gather xa -> out xb (post-LN uses blk[1])
    layer_fused<0><<<NN / 64, 256, 0, stream>>>(
        xa, rowp, rec, edge_w, edge_b, tptr, 0,
        w1t, lin1_b, ln1_g, ln1_bt, w2t, lin2_b,
        h, blk_g + 1 * HH, blk_b + 1 * HH, xb);
    // layer 1: gather xb -> out xa (post-LN uses blk[2])
    layer_fused<1><<<NN / 64, 256, 0, stream>>>(
        xb, rowp, rec, edge_w, edge_b, tptr, 1,
        w1t + 32768, lin1_b + HH2, ln1_g + HH2, ln1_bt + HH2, w2t + 32768, lin2_b + HH,
        h, blk_g + 2 * HH, blk_b + 2 * HH, xa);
    // layer 2: gather xa -> out rh (final LN uses blk[0])
    layer_fused<1><<<NN / 64, 256, 0, stream>>>(
        xa, rowp, rec, edge_w, edge_b, tptr, 2,
        w1t + 2 * 32768, lin1_b + 2 * HH2, ln1_g + 2 * HH2, ln1_bt + 2 * HH2,
        w2t + 2 * 32768, lin2_b + 2 * HH,
        h, blk_g, blk_b, rh);

    pool_kernel<<<dim3(NG, 8), 128, 0, stream>>>(rh, batch, pooled);
    head_kernel<<<NG, 128, 0, stream>>>(pooled, batch, hw1, hb1, hw2, hb2, hw3, hb3, out);
}

// Round 6
// 469.084 us; speedup vs baseline: 1.1003x; 1.1003x over previous
//
#include <hip/hip_runtime.h>
#include <math.h>

#define NN 40000
#define NE 600000
#define NG 64
#define DIM_IN 128
#define HH 128
#define HH2 256

using half8 = __attribute__((ext_vector_type(8))) _Float16;
using half4 = __attribute__((ext_vector_type(4))) _Float16;
using h2    = __attribute__((ext_vector_type(2))) _Float16;
using f4    = __attribute__((ext_vector_type(4))) float;

__device__ __forceinline__ int lower_bound_dev(const int* a, int n, int key) {
    int lo = 0, hi = n;
    while (lo < hi) { int mid = (lo + hi) >> 1; if (a[mid] < key) lo = mid + 1; else hi = mid; }
    return lo;
}

// ------- convert (x->fp16, weights->fp16 B^T) + pooled zero + count_rank, one kernel -------
#define NX (NN*DIM_IN)
#define NX4 (NX/4)
__global__ void convert_kernel(const float* __restrict__ x, const float* __restrict__ node_w,
                               const float* __restrict__ lin1_w, const float* __restrict__ lin2_w,
                               const int* __restrict__ dst, int* __restrict__ counts,
                               int* __restrict__ rank, float* __restrict__ pooled,
                               _Float16* __restrict__ xh, _Float16* __restrict__ nwt,
                               _Float16* __restrict__ w1t, _Float16* __restrict__ w2t)
{
    int id = blockIdx.x * blockDim.x + threadIdx.x;
    if (id < NX4) {
        float4 v = *(const float4*)(x + (size_t)id * 4);
        half4 o; o.x = (_Float16)v.x; o.y = (_Float16)v.y; o.z = (_Float16)v.z; o.w = (_Float16)v.w;
        *(half4*)(xh + (size_t)id * 4) = o;
        return;
    }
    id -= NX4;
    if (id < 16384) { int n = id >> 7, k = id & 127; nwt[id] = (_Float16)node_w[k*128 + n]; return; }
    id -= 16384;
    if (id < 98304) {
        int l = id >> 15, r = id & 32767;
        int n = r >> 7, k = r & 127;
        w1t[id] = (_Float16)lin1_w[l*32768 + k*256 + n];
        return;
    }
    id -= 98304;
    if (id < 98304) {
        int l = id >> 15, r = id & 32767;
        int n = r >> 8, k = r & 255;
        w2t[id] = (_Float16)lin2_w[l*32768 + k*128 + n];
        return;
    }
    id -= 98304;
    if (id < NG * HH) { pooled[id] = 0.f; return; }
    id -= NG * HH;
    if (id < NE) rank[id] = atomicAdd(&counts[dst[id]], 1);   // counts memset'd before this kernel
}

// ---------------- CSR scan (rowp from counts) ----------------
__global__ __launch_bounds__(1024) void scanA_kernel(const int* __restrict__ counts,
                                                     int* __restrict__ tmp, int* __restrict__ btot) {
    __shared__ int wpre[16];
    int t = threadIdx.x, lane = t & 63, wid = t >> 6;
    int i = blockIdx.x * 1024 + t;
    int v = (i < NN) ? counts[i] : 0;
    int s = v;
    #pragma unroll
    for (int off = 1; off < 64; off <<= 1) {
        int u = __shfl_up(s, off, 64);
        if (lane >= off) s += u;
    }
    if (lane == 63) wpre[wid] = s;
    __syncthreads();
    if (t == 0) {
        int run = 0;
        #pragma unroll
        for (int j = 0; j < 16; ++j) { int xv = wpre[j]; wpre[j] = run; run += xv; }
        btot[blockIdx.x] = run;
    }
    __syncthreads();
    if (i < NN) tmp[i] = s + wpre[wid];
}

__global__ __launch_bounds__(1024) void scanC_kernel(const int* __restrict__ tmp,
                                                     const int* __restrict__ btot,
                                                     int* __restrict__ rowp) {
    __shared__ int s_off;
    int t = threadIdx.x;
    if (t < 64) {
        int v = (t < blockIdx.x) ? btot[t] : 0;
        #pragma unroll
        for (int o = 32; o > 0; o >>= 1) v += __shfl_down(v, o, 64);
        if (t == 0) s_off = v;
    }
    __syncthreads();
    int i = blockIdx.x * 1024 + t;
    if (i < NN) rowp[i + 1] = tmp[i] + s_off;
    if (i == 0) rowp[0] = 0;
}

__global__ void fill2_kernel(const int* __restrict__ src, const int* __restrict__ dst,
                             const float* __restrict__ eattr, const int* __restrict__ rowp,
                             const int* __restrict__ rank, int2* __restrict__ rec) {
    int e = blockIdx.x * blockDim.x + threadIdx.x;
    if (e < NE) {
        int pos = rowp[dst[e]] + rank[e];
        rec[pos] = make_int2(src[e], __float_as_int(eattr[e]));
    }
}

// ------- scatter-softmax aggregation: per-wave edge stream over 16 contiguous nodes,
//         depth-16 double-buffered gather prefetch, roots cached in LDS. -------
__global__ __launch_bounds__(256) void agg_stream(
    const _Float16* __restrict__ xh,
    const int* __restrict__ rowp,
    const int2* __restrict__ rec,
    const float* __restrict__ ew, const float* __restrict__ eb,
    const float* __restrict__ tptr, int layer,
    _Float16* __restrict__ oh)
{
    __shared__ h2 roots[64 * 64];          // [node-in-block][lane], 16 KB
    int w = threadIdx.x >> 6, lane = threadIdx.x & 63;
    int d0 = blockIdx.x * 64 + w * 16;
    int c0 = 2 * lane;
    float tc = tptr[layer];
    float ew0 = ew[c0], eb0 = eb[c0];
    float ew1 = ew[c0 + 1], eb1 = eb[c0 + 1];
    #pragma unroll
    for (int i = 0; i < 16; ++i)           // prefetch roots into LDS (coalesced)
        roots[(w * 16 + i) * 64 + lane] = *(const h2*)(xh + ((size_t)(d0 + i) << 7) + c0);

    int rp_l = rowp[d0 + min(lane, 16)];
    int beg = __shfl(rp_l, 0, 64);
    int end = __shfl(rp_l, 16, 64);
    int total = end - beg;
    int cur = 0;
    int nb_rel = __shfl(rp_l, 1, 64) - beg;
    float den0 = 0.f, num0 = 0.f, den1 = 0.f, num1 = 0.f;

    auto finalize = [&]() {
        h2 rt = roots[(w * 16 + cur) * 64 + lane];
        float o0 = num0 / fmaxf(den0, 1e-16f) + (float)rt.x;
        float o1 = num1 / fmaxf(den1, 1e-16f) + (float)rt.y;
        h2 ov; ov.x = (_Float16)o0; ov.y = (_Float16)o1;
        *(h2*)(oh + ((size_t)(d0 + cur) << 7) + c0) = ov;
        den0 = num0 = den1 = num1 = 0.f;
        cur++;
        nb_rel = __shfl(rp_l, min(cur + 1, 16), 64) - beg;
    };

    if (total > 0) {
        int ms = 0; float ma = 0.f;        // current 64-edge meta chunk (regs)
        auto load_chunk = [&](int ci) {
            int jj = min(ci * 64 + lane, total - 1);
            int2 mv = rec[beg + jj];
            ms = mv.x; ma = __int_as_float(mv.y);
        };
        h2 gA[16], gB[16]; float aA[16], aB[16];
        auto issue = [&](h2* g, float* aa, int g0) {
            #pragma unroll
            for (int u = 0; u < 16; ++u) {
                int jl = min(g0 + u, total - 1) & 63;   // groups never cross 64-edge chunks
                int s = __shfl(ms, jl, 64);
                aa[u] = __shfl(ma, jl, 64);
                g[u] = *(const h2*)(xh + ((size_t)s << 7) + c0);
            }
        };
        auto consume = [&](h2* g, float* aa, int g0) {
            #pragma unroll
            for (int u = 0; u < 16; ++u) {
                int p = g0 + u;
                if (p < total) {                        // wave-uniform
                    while (cur < 16 && p == nb_rel) finalize();
                    float m0 = fmaxf(__fmaf_rn(aa[u], ew0, eb0) + (float)g[u].x, 0.f) + 1e-7f;
                    float m1 = fmaxf(__fmaf_rn(aa[u], ew1, eb1) + (float)g[u].y, 0.f) + 1e-7f;
                    float e0 = __expf(m0 * tc), e1 = __expf(m1 * tc);
                    den0 += e0; num0 = __fmaf_rn(e0, m0, num0);
                    den1 += e1; num1 = __fmaf_rn(e1, m1, num1);
                }
            }
        };
        load_chunk(0);
        issue(gA, aA, 0);
        int ng = (total + 15) >> 4;
        for (int gi = 0; gi < ng; ++gi) {
            int gn = gi + 1;
            if (gn < ng) {
                if ((gn & 3) == 0) load_chunk(gn >> 2);
                if (gi & 1) issue(gA, aA, gn << 4);
                else        issue(gB, aB, gn << 4);
            }
            if (gi & 1) consume(gB, aB, gi << 4);
            else        consume(gA, aA, gi << 4);
        }
    }
    while (cur < 16) finalize();
}

// ------------- fp16 MFMA GEMM (node linear): C half = A @ Bt^T + bias -------------
__global__ __launch_bounds__(256) void gemm_mfma(
    const _Float16* __restrict__ A, const _Float16* __restrict__ Bt,
    const float* __restrict__ bias, _Float16* __restrict__ C,
    int M, int N, int K)
{
    constexpr int LDA = 40;
    __shared__ _Float16 As[64 * LDA];
    __shared__ _Float16 Bs[128 * LDA];
    int t = threadIdx.x;
    int row0 = blockIdx.y * 64;
    int col0 = blockIdx.x * 128;
    int w = t >> 6, lane = t & 63;
    int wm = w & 1, wn = w >> 1;
    int q = lane >> 4, l16 = lane & 15;
    f4 acc[2][4];
    #pragma unroll
    for (int i = 0; i < 2; ++i)
        #pragma unroll
        for (int j = 0; j < 4; ++j)
            acc[i][j] = (f4){0.f, 0.f, 0.f, 0.f};

    for (int k0 = 0; k0 < K; k0 += 32) {
        {
            int r = t >> 2, seg = t & 3;
            *(float4*)&As[r * LDA + seg * 8] =
                *(const float4*)(A + (size_t)(row0 + r) * K + k0 + seg * 8);
        }
        #pragma unroll
        for (int i = 0; i < 2; ++i) {
            int idx = t + i * 256;
            int r = idx >> 2, seg = idx & 3;
            *(float4*)&Bs[r * LDA + seg * 8] =
                *(const float4*)(Bt + (size_t)(col0 + r) * K + k0 + seg * 8);
        }
        __syncthreads();
        half8 af[2], bf[4];
        #pragma unroll
        for (int i = 0; i < 2; ++i)
            af[i] = *(const half8*)&As[(wm * 32 + i * 16 + l16) * LDA + q * 8];
        #pragma unroll
        for (int j = 0; j < 4; ++j)
            bf[j] = *(const half8*)&Bs[(wn * 64 + j * 16 + l16) * LDA + q * 8];
        #pragma unroll
        for (int i = 0; i < 2; ++i)
            #pragma unroll
            for (int j = 0; j < 4; ++j)
                acc[i][j] = __builtin_amdgcn_mfma_f32_16x16x32_f16(af[i], bf[j], acc[i][j], 0, 0, 0);
        __syncthreads();
    }
    #pragma unroll
    for (int j = 0; j < 4; ++j) {
        int col = col0 + wn * 64 + j * 16 + l16;
        float bv = bias[col];
        #pragma unroll
        for (int i = 0; i < 2; ++i) {
            int rbase = row0 + wm * 32 + i * 16 + q * 4;
            #pragma unroll
            for (int rg = 0; rg < 4; ++rg)
                C[(size_t)(rbase + rg) * N + col] = (_Float16)(acc[i][j][rg] + bv);
        }
    }
}

// ------- fused MLP: lin1 -> LN1 -> ReLU -> lin2 (+bias) [+res] -> h; blockLN -> ReLU -> xout
//         64 rows/block, 256 threads; As unions midh (XOR swizzle) -> 54.3 KB LDS, 3 blk/CU -------
template<int RES>
__global__ __launch_bounds__(256) void mlp_fused(
    const _Float16* __restrict__ Ain,
    const _Float16* __restrict__ w1t, const float* __restrict__ b1,
    const float* __restrict__ g1, const float* __restrict__ bt1,
    const _Float16* __restrict__ w2t, const float* __restrict__ b2,
    float* __restrict__ h,
    const float* __restrict__ bg, const float* __restrict__ bb,
    _Float16* __restrict__ xout)
{
    constexpr int LDA = 136;
    constexpr int LDB = 40;
    __shared__ __align__(16) char smem[54272];
    _Float16* As   = (_Float16*)smem;          // 17408 B, dead after lin1
    _Float16* midh = (_Float16*)smem;          // 32768 B (XOR swizzled), unions As
    _Float16* Bs   = (_Float16*)(smem + 32768);
    float* ssum    = (float*)(smem + 53248);
    float* ssum2   = (float*)(smem + 53760);
    int t = threadIdx.x;
    int row0 = blockIdx.x * 64;
    int w = t >> 6, lane = t & 63;
    int wm = w & 1, wn = w >> 1;
    int q = lane >> 4, l16 = lane & 15;

    #pragma unroll
    for (int p = 0; p < 4; ++p) {              // stage A fully: 64 x 128 halves
        int idx = t + p * 256;
        int r = idx >> 4, seg = idx & 15;
        *(float4*)&As[r * LDA + seg * 8] =
            *(const float4*)(Ain + (size_t)(row0 + r) * 128 + seg * 8);
    }

    f4 acc[2][8];
    #pragma unroll
    for (int i = 0; i < 2; ++i)
        #pragma unroll
        for (int j = 0; j < 8; ++j)
            acc[i][j] = (f4){0.f, 0.f, 0.f, 0.f};
    for (int k0 = 0; k0 < 128; k0 += 32) {
        #pragma unroll
        for (int p = 0; p < 4; ++p) {          // stage B1 tile [256][32]
            int idx = t + p * 256;
            int r = idx >> 2, seg = idx & 3;
            *(float4*)&Bs[r * LDB + seg * 8] =
                *(const float4*)(w1t + (size_t)r * 128 + k0 + seg * 8);
        }
        __syncthreads();
        half8 af[2], bf[8];
        #pragma unroll
        for (int i = 0; i < 2; ++i)
            af[i] = *(const half8*)&As[(wm * 32 + i * 16 + l16) * LDA + k0 + q * 8];
        #pragma unroll
        for (int j = 0; j < 8; ++j)
            bf[j] = *(const half8*)&Bs[(wn * 128 + j * 16 + l16) * LDB + q * 8];
        #pragma unroll
        for (int i = 0; i < 2; ++i)
            #pragma unroll
            for (int j = 0; j < 8; ++j)
                acc[i][j] = __builtin_amdgcn_mfma_f32_16x16x32_f16(af[i], bf[j], acc[i][j], 0, 0, 0);
        __syncthreads();
    }

    float b1v[8], g1v[8], bt1v[8];
    #pragma unroll
    for (int j = 0; j < 8; ++j) {
        int col = wn * 128 + j * 16 + l16;
        b1v[j] = b1[col]; g1v[j] = g1[col]; bt1v[j] = bt1[col];
    }
    float vals[2][8][4];
    #pragma unroll
    for (int i = 0; i < 2; ++i)
        #pragma unroll
        for (int j = 0; j < 8; ++j)
            #pragma unroll
            for (int rg = 0; rg < 4; ++rg)
                vals[i][j][rg] = acc[i][j][rg] + b1v[j];
    #pragma unroll
    for (int i = 0; i < 2; ++i) {
        #pragma unroll
        for (int rg = 0; rg < 4; ++rg) {
            float ps = 0.f, ps2 = 0.f;
            #pragma unroll
            for (int j = 0; j < 8; ++j) { float v = vals[i][j][rg]; ps += v; ps2 += v * v; }
            #pragma unroll
            for (int off = 1; off < 16; off <<= 1) {
                ps  += __shfl_xor(ps,  off, 16);
                ps2 += __shfl_xor(ps2, off, 16);
            }
            if (l16 == 0) {
                int row = wm * 32 + i * 16 + q * 4 + rg;
                ssum[row * 2 + wn] = ps; ssum2[row * 2 + wn] = ps2;
            }
        }
    }
    __syncthreads();   // stats ready; also separates last As read from midh writes (union)
    #pragma unroll
    for (int i = 0; i < 2; ++i) {
        #pragma unroll
        for (int rg = 0; rg < 4; ++rg) {
            int row = wm * 32 + i * 16 + q * 4 + rg;
            float S = ssum[row * 2 + 0] + ssum[row * 2 + 1];
            float S2 = ssum2[row * 2 + 0] + ssum2[row * 2 + 1];
            float mu = S * (1.0f / 256.0f);
            float var = S2 * (1.0f / 256.0f) - mu * mu;
            float rstd = rsqrtf(var + 1e-5f);
            #pragma unroll
            for (int j = 0; j < 8; ++j) {
                int col = wn * 128 + j * 16 + l16;
                float o = fmaxf((vals[i][j][rg] - mu) * rstd * g1v[j] + bt1v[j], 0.f);
                int pg = (col >> 3) ^ (row & 31);          // XOR-swizzled midh
                midh[row * 256 + (pg << 3) + (col & 7)] = (_Float16)o;
            }
        }
    }
    __syncthreads();

    f4 acc2[2][4];
    #pragma unroll
    for (int i = 0; i < 2; ++i)
        #pragma unroll
        for (int j = 0; j < 4; ++j)
            acc2[i][j] = (f4){0.f, 0.f, 0.f, 0.f};
    for (int k0 = 0; k0 < 256; k0 += 32) {
        #pragma unroll
        for (int p = 0; p < 2; ++p) {          // stage B2 tile [128][32]
            int idx = t + p * 256;
            int r = idx >> 2, seg = idx & 3;
            *(float4*)&Bs[r * LDB + seg * 8] =
                *(const float4*)(w2t + (size_t)r * 256 + k0 + seg * 8);
        }
        __syncthreads();
        half8 af2[2], bf2[4];
        #pragma unroll
        for (int i = 0; i < 2; ++i) {
            int rr = wm * 32 + i * 16 + l16;
            int pg = ((k0 >> 3) + q) ^ (rr & 31);
            af2[i] = *(const half8*)&midh[rr * 256 + (pg << 3)];
        }
        #pragma unroll
        for (int j = 0; j < 4; ++j)
            bf2[j] = *(const half8*)&Bs[(wn * 64 + j * 16 + l16) * LDB + q * 8];
        #pragma unroll
        for (int i = 0; i < 2; ++i)
            #pragma unroll
            for (int j = 0; j < 4; ++j)
                acc2[i][j] = __builtin_amdgcn_mfma_f32_16x16x32_f16(af2[i], bf2[j], acc2[i][j], 0, 0, 0);
        __syncthreads();
    }

    float b2v[4], bgv[4], bbv[4];
    #pragma unroll
    for (int j = 0; j < 4; ++j) {
        int col = wn * 64 + j * 16 + l16;
        b2v[j] = b2[col]; bgv[j] = bg[col]; bbv[j] = bb[col];
    }
    float ov[2][4][4];
    #pragma unroll
    for (int i = 0; i < 2; ++i) {
        #pragma unroll
        for (int rg = 0; rg < 4; ++rg) {
            int row = wm * 32 + i * 16 + q * 4 + rg;
            #pragma unroll
            for (int j = 0; j < 4; ++j) {
                int col = wn * 64 + j * 16 + l16;
                float v = acc2[i][j][rg] + b2v[j];
                size_t gidx = (size_t)(row0 + row) * 128 + col;
                if (RES) v += h[gidx];
                h[gidx] = v;
                ov[i][j][rg] = v;
            }
        }
    }
    #pragma unroll
    for (int i = 0; i < 2; ++i) {
        #pragma unroll
        for (int rg = 0; rg < 4; ++rg) {
            float ps = 0.f, ps2 = 0.f;
            #pragma unroll
            for (int j = 0; j < 4; ++j) { float v = ov[i][j][rg]; ps += v; ps2 += v * v; }
            #pragma unroll
            for (int off = 1; off < 16; off <<= 1) {
                ps  += __shfl_xor(ps,  off, 16);
                ps2 += __shfl_xor(ps2, off, 16);
            }
            if (l16 == 0) {
                int row = wm * 32 + i * 16 + q * 4 + rg;
                ssum[row * 2 + wn] = ps; ssum2[row * 2 + wn] = ps2;
            }
        }
    }
    __syncthreads();
    #pragma unroll
    for (int i = 0; i < 2; ++i) {
        #pragma unroll
        for (int rg = 0; rg < 4; ++rg) {
            int row = wm * 32 + i * 16 + q * 4 + rg;
            float S = ssum[row * 2 + 0] + ssum[row * 2 + 1];
            float S2 = ssum2[row * 2 + 0] + ssum2[row * 2 + 1];
            float mu = S * (1.0f / 128.0f);
            float var = S2 * (1.0f / 128.0f) - mu * mu;
            float rstd = rsqrtf(var + 1e-5f);
            #pragma unroll
            for (int j = 0; j < 4; ++j) {
                int col = wn * 64 + j * 16 + l16;
                float o = fmaxf((ov[i][j][rg] - mu) * rstd * bgv[j] + bbv[j], 0.f);
                xout[(size_t)(row0 + row) * 128 + col] = (_Float16)o;
            }
        }
    }
}

// ------------- mean pool over sorted batch (half input) -------------
__global__ __launch_bounds__(128) void pool_kernel(
    const _Float16* __restrict__ f, const int* __restrict__ batch, float* __restrict__ pooled)
{
    int g = blockIdx.x;
    int chunk = blockIdx.y;
    int c = threadIdx.x;
    int s = lower_bound_dev(batch, NN, g);
    int e = lower_bound_dev(batch, NN, g + 1);
    int len = e - s;
    if (len <= 0) return;
    int nch = gridDim.y;
    int per = (len + nch - 1) / nch;
    int cs = s + chunk * per;
    int ce = min(cs + per, e);
    if (cs >= ce) return;
    float acc = 0.f;
    for (int n = cs; n < ce; ++n) acc += (float)f[(size_t)n * HH + c];
    atomicAdd(&pooled[g * HH + c], acc);
}

// ------------- MLP head -------------
__global__ __launch_bounds__(128) void head_kernel(
    const float* __restrict__ pooled, const int* __restrict__ batch,
    const float* __restrict__ hw1, const float* __restrict__ hb1,
    const float* __restrict__ hw2, const float* __restrict__ hb2,
    const float* __restrict__ hw3, const float* __restrict__ hb3,
    float* __restrict__ out)
{
    __shared__ float p[HH];
    __shared__ float o1[64];
    __shared__ float o2[32];
    int g = blockIdx.x;
    int t = threadIdx.x;
    int s = lower_bound_dev(batch, NN, g);
    int e = lower_bound_dev(batch, NN, g + 1);
    float cnt = fmaxf((float)(e - s), 1.0f);
    p[t] = pooled[g * HH + t] / cnt;
    __syncthreads();
    if (t < 64) {
        float acc = hb1[t];
        for (int k = 0; k < HH; ++k) acc += p[k] * hw1[k * 64 + t];
        o1[t] = fmaxf(acc, 0.f);
    }
    __syncthreads();
    if (t < 32) {
        float acc = hb2[t];
        for (int k = 0; k < 64; ++k) acc += o1[k] * hw2[k * 32 + t];
        o2[t] = fmaxf(acc, 0.f);
    }
    __syncthreads();
    if (t == 0) {
        float acc = hb3[0];
        for (int k = 0; k < 32; ++k) acc += o2[k] * hw3[k];
        out[g] = acc;
    }
}

extern "C" void kernel_launch(void* const* d_in, const int* in_sizes, int n_in,
                              void* d_out, int out_size, void* d_ws, size_t ws_size,
                              hipStream_t stream)
{
    const float* x      = (const float*)d_in[0];
    const float* eattr  = (const float*)d_in[1];
    const float* node_w = (const float*)d_in[2];
    const float* node_b = (const float*)d_in[3];
    const float* edge_w = (const float*)d_in[4];
    const float* edge_b = (const float*)d_in[5];
    const float* tptr   = (const float*)d_in[6];
    const float* lin1_w = (const float*)d_in[7];
    const float* lin1_b = (const float*)d_in[8];
    const float* ln1_g  = (const float*)d_in[9];
    const float* ln1_bt = (const float*)d_in[10];
    const float* lin2_w = (const float*)d_in[11];
    const float* lin2_b = (const float*)d_in[12];
    const float* blk_g  = (const float*)d_in[13];
    const float* blk_b  = (const float*)d_in[14];
    const float* hw1    = (const float*)d_in[15];
    const float* hb1    = (const float*)d_in[16];
    const float* hw2    = (const float*)d_in[17];
    const float* hb2    = (const float*)d_in[18];
    const float* hw3    = (const float*)d_in[19];
    const float* hb3    = (const float*)d_in[20];
    const int*   eidx   = (const int*)d_in[21];
    const int*   batch  = (const int*)d_in[22];
    const int* src = eidx;
    const int* dst = eidx + NE;
    float* out = (float*)d_out;

    char* ws = (char*)d_ws;
    size_t off = 0;
    auto carve = [&](size_t bytes) -> char* {
        char* p = ws + off;
        off = (off + bytes + 255) & ~(size_t)255;
        return p;
    };
    float*    h      = (float*)carve((size_t)NN * HH * 4);
    _Float16* xh_in  = (_Float16*)carve((size_t)NX * 2);
    _Float16* xa     = (_Float16*)carve((size_t)NN * HH * 2);
    _Float16* xb     = (_Float16*)carve((size_t)NN * HH * 2);
    _Float16* oh     = (_Float16*)carve((size_t)NN * HH * 2);
    _Float16* rh     = (_Float16*)carve((size_t)NN * HH * 2);
    _Float16* nwt    = (_Float16*)carve((size_t)16384 * 2);
    _Float16* w1t    = (_Float16*)carve((size_t)98304 * 2);
    _Float16* w2t    = (_Float16*)carve((size_t)98304 * 2);
    int*      counts = (int*)carve((size_t)NN * 4);
    int*      rank   = (int*)carve((size_t)NE * 4);
    int*      tmp    = (int*)carve((size_t)NN * 4);
    int*      btot   = (int*)carve((size_t)64 * 4);
    int*      rowp   = (int*)carve((size_t)(NN + 1) * 4);
    int2*     rec    = (int2*)carve((size_t)NE * 8);
    float*    pooled = (float*)carve((size_t)NG * HH * 4);

    hipMemsetAsync(counts, 0, (size_t)NN * 4, stream);

    {   // convert + pooled-zero + count_rank
        int total = NX4 + 16384 + 98304 + 98304 + NG * HH + NE;
        convert_kernel<<<(total + 255) / 256, 256, 0, stream>>>(
            x, node_w, lin1_w, lin2_w, dst, counts, rank, pooled, xh_in, nwt, w1t, w2t);
    }
    const int NB = (NN + 1023) / 1024;   // 40
    scanA_kernel<<<NB, 1024, 0, stream>>>(counts, tmp, btot);
    scanC_kernel<<<NB, 1024, 0, stream>>>(tmp, btot, rowp);
    fill2_kernel<<<(NE + 255) / 256, 256, 0, stream>>>(src, dst, eattr, rowp, rank, rec);

    // node linear: xa = half(x @ node_w + node_b)
    gemm_mfma<<<dim3(1, NN / 64), 256, 0, stream>>>(xh_in, nwt, node_b, xa, NN, HH, DIM_IN);

    // layer 0: agg(xa) -> oh; MLP -> h, xb (post-LN uses blk[1])
    agg_stream<<<NN / 64, 256, 0, stream>>>(xa, rowp, rec, edge_w, edge_b, tptr, 0, oh);
    mlp_fused<0><<<NN / 64, 256, 0, stream>>>(
        oh, w1t, lin1_b, ln1_g, ln1_bt, w2t, lin2_b,
        h, blk_g + 1 * HH, blk_b + 1 * HH, xb);
    // layer 1: agg(xb) -> oh; MLP (+res) -> h, xa (post-LN uses blk[2])
    agg_stream<<<NN / 64, 256, 0, stream>>>(xb, rowp, rec, edge_w, edge_b, tptr, 1, oh);
    mlp_fused<1><<<NN / 64, 256, 0, stream>>>(
        oh, w1t + 32768, lin1_b + HH2, ln1_g + HH2, ln1_bt + HH2, w2t + 32768, lin2_b + HH,
        h, blk_g + 2 * HH, blk_b + 2 * HH, xa);
    // layer 2: agg(xa) -> oh; MLP (+res) -> h, rh (final LN uses blk[0])
    agg_stream<<<NN / 64, 256, 0, stream>>>(xa, rowp, rec, edge_w, edge_b, tptr, 2, oh);
    mlp_fused<1><<<NN / 64, 256, 0, stream>>>(
        oh, w1t + 2 * 32768, lin1_b + 2 * HH2, ln1_g + 2 * HH2, ln1_bt + 2 * HH2,
        w2t + 2 * 32768, lin2_b + 2 * HH,
        h, blk_g, blk_b, rh);

    pool_kernel<<<dim3(NG, 8), 128, 0, stream>>>(rh, batch, pooled);
    head_kernel<<<NG, 128, 0, stream>>>(pooled, batch, hw1, hb1, hw2, hb2, hw3, hb3, out);
}

// Round 7
// 404.824 us; speedup vs baseline: 1.2750x; 1.1587x over previous
//
#include <hip/hip_runtime.h>
#include <math.h>

#define NN 40000
#define NE 600000
#define NG 64
#define DIM_IN 128
#define HH 128
#define HH2 256

using half8 = __attribute__((ext_vector_type(8))) _Float16;
using half4 = __attribute__((ext_vector_type(4))) _Float16;
using h2    = __attribute__((ext_vector_type(2))) _Float16;
using f4    = __attribute__((ext_vector_type(4))) float;

__device__ __forceinline__ int lower_bound_dev(const int* a, int n, int key) {
    int lo = 0, hi = n;
    while (lo < hi) { int mid = (lo + hi) >> 1; if (a[mid] < key) lo = mid + 1; else hi = mid; }
    return lo;
}

// ------- convert (x->fp16, weights->fp16 B^T) + pooled zero + count_rank, one kernel -------
#define NX (NN*DIM_IN)
#define NX4 (NX/4)
__global__ void convert_kernel(const float* __restrict__ x, const float* __restrict__ node_w,
                               const float* __restrict__ lin1_w, const float* __restrict__ lin2_w,
                               const int* __restrict__ dst, int* __restrict__ counts,
                               int* __restrict__ rank, float* __restrict__ pooled,
                               _Float16* __restrict__ xh, _Float16* __restrict__ nwt,
                               _Float16* __restrict__ w1t, _Float16* __restrict__ w2t)
{
    int id = blockIdx.x * blockDim.x + threadIdx.x;
    if (id < NX4) {
        float4 v = *(const float4*)(x + (size_t)id * 4);
        half4 o; o.x = (_Float16)v.x; o.y = (_Float16)v.y; o.z = (_Float16)v.z; o.w = (_Float16)v.w;
        *(half4*)(xh + (size_t)id * 4) = o;
        return;
    }
    id -= NX4;
    if (id < 16384) { int n = id >> 7, k = id & 127; nwt[id] = (_Float16)node_w[k*128 + n]; return; }
    id -= 16384;
    if (id < 98304) {
        int l = id >> 15, r = id & 32767;
        int n = r >> 7, k = r & 127;
        w1t[id] = (_Float16)lin1_w[l*32768 + k*256 + n];
        return;
    }
    id -= 98304;
    if (id < 98304) {
        int l = id >> 15, r = id & 32767;
        int n = r >> 8, k = r & 255;
        w2t[id] = (_Float16)lin2_w[l*32768 + k*128 + n];
        return;
    }
    id -= 98304;
    if (id < NG * HH) { pooled[id] = 0.f; return; }
    id -= NG * HH;
    if (id < NE) rank[id] = atomicAdd(&counts[dst[id]], 1);   // counts memset'd before this kernel
}

// ---------------- CSR scan (rowp from counts) ----------------
__global__ __launch_bounds__(1024) void scanA_kernel(const int* __restrict__ counts,
                                                     int* __restrict__ tmp, int* __restrict__ btot) {
    __shared__ int wpre[16];
    int t = threadIdx.x, lane = t & 63, wid = t >> 6;
    int i = blockIdx.x * 1024 + t;
    int v = (i < NN) ? counts[i] : 0;
    int s = v;
    #pragma unroll
    for (int off = 1; off < 64; off <<= 1) {
        int u = __shfl_up(s, off, 64);
        if (lane >= off) s += u;
    }
    if (lane == 63) wpre[wid] = s;
    __syncthreads();
    if (t == 0) {
        int run = 0;
        #pragma unroll
        for (int j = 0; j < 16; ++j) { int xv = wpre[j]; wpre[j] = run; run += xv; }
        btot[blockIdx.x] = run;
    }
    __syncthreads();
    if (i < NN) tmp[i] = s + wpre[wid];
}

__global__ __launch_bounds__(1024) void scanC_kernel(const int* __restrict__ tmp,
                                                     const int* __restrict__ btot,
                                                     int* __restrict__ rowp) {
    __shared__ int s_off;
    int t = threadIdx.x;
    if (t < 64) {
        int v = (t < blockIdx.x) ? btot[t] : 0;
        #pragma unroll
        for (int o = 32; o > 0; o >>= 1) v += __shfl_down(v, o, 64);
        if (t == 0) s_off = v;
    }
    __syncthreads();
    int i = blockIdx.x * 1024 + t;
    if (i < NN) rowp[i + 1] = tmp[i] + s_off;
    if (i == 0) rowp[0] = 0;
}

__global__ void fill2_kernel(const int* __restrict__ src, const int* __restrict__ dst,
                             const float* __restrict__ eattr, const int* __restrict__ rowp,
                             const int* __restrict__ rank, int2* __restrict__ rec) {
    int e = blockIdx.x * blockDim.x + threadIdx.x;
    if (e < NE) {
        int pos = rowp[dst[e]] + rank[e];
        rec[pos] = make_int2(src[e], __float_as_int(eattr[e]));
    }
}

// ------- scatter-softmax aggregation: 1 node/wave, 4 nodes/block (max TLP),
//         double-buffered prefetch-8 gathers (r4 structure — best measured) -------
__global__ __launch_bounds__(256) void agg_kernel(
    const _Float16* __restrict__ xh,
    const int* __restrict__ row_ptr,
    const int2* __restrict__ rec,
    const float* __restrict__ ew, const float* __restrict__ eb,
    const float* __restrict__ tptr, int layer,
    _Float16* __restrict__ oh)
{
    int d = blockIdx.x * 4 + (threadIdx.x >> 6);
    int lane = threadIdx.x & 63;
    int c0 = 2 * lane;
    float tc = tptr[layer];
    float ew0 = ew[c0], eb0 = eb[c0];
    float ew1 = ew[c0 + 1], eb1 = eb[c0 + 1];
    int beg = row_ptr[d], end = row_ptr[d + 1];
    float den0 = 0.f, num0 = 0.f, den1 = 0.f, num1 = 0.f;
    for (int base = beg; base < end; base += 64) {
        int cnt = min(64, end - base);
        int2 mv = rec[base + min(lane, cnt - 1)];   // 64 edges' meta in one coalesced load
        int sv = mv.x;
        float av = __int_as_float(mv.y);
        h2 gA[8], gB[8]; float aA[8], aB[8];
        auto issue = [&](h2 (&g)[8], float (&aa)[8], int j0) {
            #pragma unroll
            for (int u = 0; u < 8; ++u) {
                int jj = min(j0 + u, cnt - 1);
                int s = __shfl(sv, jj, 64);
                aa[u] = __shfl(av, jj, 64);
                g[u] = *(const h2*)(xh + ((size_t)s << 7) + c0);
            }
        };
        auto consume = [&](h2 (&g)[8], float (&aa)[8], int j0) {
            int lim = min(8, cnt - j0);
            #pragma unroll
            for (int u = 0; u < 8; ++u) {
                if (u < lim) {   // wave-uniform predicate
                    float m0 = fmaxf(__fmaf_rn(aa[u], ew0, eb0) + (float)g[u].x, 0.f) + 1e-7f;
                    float m1 = fmaxf(__fmaf_rn(aa[u], ew1, eb1) + (float)g[u].y, 0.f) + 1e-7f;
                    float e0 = __expf(m0 * tc), e1 = __expf(m1 * tc);
                    den0 += e0; num0 = __fmaf_rn(e0, m0, num0);
                    den1 += e1; num1 = __fmaf_rn(e1, m1, num1);
                }
            }
        };
        issue(gA, aA, 0);
        for (int j0 = 0; j0 < cnt; j0 += 16) {
            if (j0 + 8 < cnt)  issue(gB, aB, j0 + 8);
            consume(gA, aA, j0);
            if (j0 + 16 < cnt) issue(gA, aA, j0 + 16);
            if (j0 + 8 < cnt)  consume(gB, aB, j0 + 8);
        }
    }
    h2 sv2 = *(const h2*)(xh + ((size_t)d << 7) + c0);
    float o0 = num0 / fmaxf(den0, 1e-16f) + (float)sv2.x;
    float o1 = num1 / fmaxf(den1, 1e-16f) + (float)sv2.y;
    h2 ov; ov.x = (_Float16)o0; ov.y = (_Float16)o1;
    *(h2*)(oh + ((size_t)d << 7) + c0) = ov;
}

// ------------- fp16 MFMA GEMM (node linear): C half = A @ Bt^T + bias -------------
__global__ __launch_bounds__(256) void gemm_mfma(
    const _Float16* __restrict__ A, const _Float16* __restrict__ Bt,
    const float* __restrict__ bias, _Float16* __restrict__ C,
    int M, int N, int K)
{
    constexpr int LDA = 40;
    __shared__ _Float16 As[64 * LDA];
    __shared__ _Float16 Bs[128 * LDA];
    int t = threadIdx.x;
    int row0 = blockIdx.y * 64;
    int col0 = blockIdx.x * 128;
    int w = t >> 6, lane = t & 63;
    int wm = w & 1, wn = w >> 1;
    int q = lane >> 4, l16 = lane & 15;
    f4 acc[2][4];
    #pragma unroll
    for (int i = 0; i < 2; ++i)
        #pragma unroll
        for (int j = 0; j < 4; ++j)
            acc[i][j] = (f4){0.f, 0.f, 0.f, 0.f};

    for (int k0 = 0; k0 < K; k0 += 32) {
        {
            int r = t >> 2, seg = t & 3;
            *(float4*)&As[r * LDA + seg * 8] =
                *(const float4*)(A + (size_t)(row0 + r) * K + k0 + seg * 8);
        }
        #pragma unroll
        for (int i = 0; i < 2; ++i) {
            int idx = t + i * 256;
            int r = idx >> 2, seg = idx & 3;
            *(float4*)&Bs[r * LDA + seg * 8] =
                *(const float4*)(Bt + (size_t)(col0 + r) * K + k0 + seg * 8);
        }
        __syncthreads();
        half8 af[2], bf[4];
        #pragma unroll
        for (int i = 0; i < 2; ++i)
            af[i] = *(const half8*)&As[(wm * 32 + i * 16 + l16) * LDA + q * 8];
        #pragma unroll
        for (int j = 0; j < 4; ++j)
            bf[j] = *(const half8*)&Bs[(wn * 64 + j * 16 + l16) * LDA + q * 8];
        #pragma unroll
        for (int i = 0; i < 2; ++i)
            #pragma unroll
            for (int j = 0; j < 4; ++j)
                acc[i][j] = __builtin_amdgcn_mfma_f32_16x16x32_f16(af[i], bf[j], acc[i][j], 0, 0, 0);
        __syncthreads();
    }
    #pragma unroll
    for (int j = 0; j < 4; ++j) {
        int col = col0 + wn * 64 + j * 16 + l16;
        float bv = bias[col];
        #pragma unroll
        for (int i = 0; i < 2; ++i) {
            int rbase = row0 + wm * 32 + i * 16 + q * 4;
            #pragma unroll
            for (int rg = 0; rg < 4; ++rg)
                C[(size_t)(rbase + rg) * N + col] = (_Float16)(acc[i][j][rg] + bv);
        }
    }
}

// ------- fused MLP: lin1 -> LN1 -> ReLU -> lin2 (+bias) [+res] -> h; blockLN -> ReLU -> xout
//         B fragments DIRECT from global (L2-hot weights) — no B-staging barriers.
//         LDS = As union midh + stats = 33.8 KB -> 4 blocks/CU. 4 syncthreads total. -------
template<int RES>
__global__ __launch_bounds__(256, 4) void mlp_fused(
    const _Float16* __restrict__ Ain,
    const _Float16* __restrict__ w1t, const float* __restrict__ b1,
    const float* __restrict__ g1, const float* __restrict__ bt1,
    const _Float16* __restrict__ w2t, const float* __restrict__ b2,
    float* __restrict__ h,
    const float* __restrict__ bg, const float* __restrict__ bb,
    _Float16* __restrict__ xout)
{
    constexpr int LDA = 136;
    __shared__ __align__(16) char smem[33792];
    _Float16* As   = (_Float16*)smem;          // 17408 B, dead after lin1
    _Float16* midh = (_Float16*)smem;          // 32768 B (XOR swizzled), unions As
    float* ssum    = (float*)(smem + 32768);   // [64][2]
    float* ssum2   = (float*)(smem + 33280);   // [64][2]
    int t = threadIdx.x;
    int row0 = blockIdx.x * 64;
    int w = t >> 6, lane = t & 63;
    int wm = w & 1, wn = w >> 1;
    int q = lane >> 4, l16 = lane & 15;

    #pragma unroll
    for (int p = 0; p < 4; ++p) {              // stage A fully: 64 x 128 halves
        int idx = t + p * 256;
        int r = idx >> 4, seg = idx & 15;
        *(float4*)&As[r * LDA + seg * 8] =
            *(const float4*)(Ain + (size_t)(row0 + r) * 128 + seg * 8);
    }
    __syncthreads();                            // (1) A staged

    // ---- lin1: acc[2][8] over K=128; B1 direct from global ----
    f4 acc[2][8];
    #pragma unroll
    for (int i = 0; i < 2; ++i)
        #pragma unroll
        for (int j = 0; j < 8; ++j)
            acc[i][j] = (f4){0.f, 0.f, 0.f, 0.f};
    #pragma unroll
    for (int k0 = 0; k0 < 128; k0 += 32) {
        half8 af[2], bf[8];
        #pragma unroll
        for (int i = 0; i < 2; ++i)
            af[i] = *(const half8*)&As[(wm * 32 + i * 16 + l16) * LDA + k0 + q * 8];
        #pragma unroll
        for (int j = 0; j < 8; ++j)
            bf[j] = *(const half8*)(w1t + (size_t)(wn * 128 + j * 16 + l16) * 128 + k0 + q * 8);
        #pragma unroll
        for (int i = 0; i < 2; ++i)
            #pragma unroll
            for (int j = 0; j < 8; ++j)
                acc[i][j] = __builtin_amdgcn_mfma_f32_16x16x32_f16(af[i], bf[j], acc[i][j], 0, 0, 0);
    }

    // ---- bias + LN1 stats (rows of 256) ----
    float b1v[8], g1v[8], bt1v[8];
    #pragma unroll
    for (int j = 0; j < 8; ++j) {
        int col = wn * 128 + j * 16 + l16;
        b1v[j] = b1[col]; g1v[j] = g1[col]; bt1v[j] = bt1[col];
    }
    float vals[2][8][4];
    #pragma unroll
    for (int i = 0; i < 2; ++i)
        #pragma unroll
        for (int j = 0; j < 8; ++j)
            #pragma unroll
            for (int rg = 0; rg < 4; ++rg)
                vals[i][j][rg] = acc[i][j][rg] + b1v[j];
    #pragma unroll
    for (int i = 0; i < 2; ++i) {
        #pragma unroll
        for (int rg = 0; rg < 4; ++rg) {
            float ps = 0.f, ps2 = 0.f;
            #pragma unroll
            for (int j = 0; j < 8; ++j) { float v = vals[i][j][rg]; ps += v; ps2 += v * v; }
            #pragma unroll
            for (int off = 1; off < 16; off <<= 1) {
                ps  += __shfl_xor(ps,  off, 16);
                ps2 += __shfl_xor(ps2, off, 16);
            }
            if (l16 == 0) {
                int row = wm * 32 + i * 16 + q * 4 + rg;
                ssum[row * 2 + wn] = ps; ssum2[row * 2 + wn] = ps2;
            }
        }
    }
    __syncthreads();                            // (2) stats ready; As reads done (midh union safe)
    #pragma unroll
    for (int i = 0; i < 2; ++i) {
        #pragma unroll
        for (int rg = 0; rg < 4; ++rg) {
            int row = wm * 32 + i * 16 + q * 4 + rg;
            float S = ssum[row * 2 + 0] + ssum[row * 2 + 1];
            float S2 = ssum2[row * 2 + 0] + ssum2[row * 2 + 1];
            float mu = S * (1.0f / 256.0f);
            float var = S2 * (1.0f / 256.0f) - mu * mu;
            float rstd = rsqrtf(var + 1e-5f);
            #pragma unroll
            for (int j = 0; j < 8; ++j) {
                int col = wn * 128 + j * 16 + l16;
                float o = fmaxf((vals[i][j][rg] - mu) * rstd * g1v[j] + bt1v[j], 0.f);
                int pg = (col >> 3) ^ (row & 31);          // XOR-swizzled midh
                midh[row * 256 + (pg << 3) + (col & 7)] = (_Float16)o;
            }
        }
    }
    __syncthreads();                            // (3) midh ready

    // ---- lin2: acc2[2][4] over K=256; B2 direct from global ----
    f4 acc2[2][4];
    #pragma unroll
    for (int i = 0; i < 2; ++i)
        #pragma unroll
        for (int j = 0; j < 4; ++j)
            acc2[i][j] = (f4){0.f, 0.f, 0.f, 0.f};
    #pragma unroll
    for (int k0 = 0; k0 < 256; k0 += 32) {
        half8 af2[2], bf2[4];
        #pragma unroll
        for (int i = 0; i < 2; ++i) {
            int rr = wm * 32 + i * 16 + l16;
            int pg = ((k0 >> 3) + q) ^ (rr & 31);
            af2[i] = *(const half8*)&midh[rr * 256 + (pg << 3)];
        }
        #pragma unroll
        for (int j = 0; j < 4; ++j)
            bf2[j] = *(const half8*)(w2t + (size_t)(wn * 64 + j * 16 + l16) * 256 + k0 + q * 8);
        #pragma unroll
        for (int i = 0; i < 2; ++i)
            #pragma unroll
            for (int j = 0; j < 4; ++j)
                acc2[i][j] = __builtin_amdgcn_mfma_f32_16x16x32_f16(af2[i], bf2[j], acc2[i][j], 0, 0, 0);
    }

    // ---- epilogue: bias (+res) -> h; block LN + ReLU -> xout ----
    float b2v[4], bgv[4], bbv[4];
    #pragma unroll
    for (int j = 0; j < 4; ++j) {
        int col = wn * 64 + j * 16 + l16;
        b2v[j] = b2[col]; bgv[j] = bg[col]; bbv[j] = bb[col];
    }
    float ov[2][4][4];
    #pragma unroll
    for (int i = 0; i < 2; ++i) {
        #pragma unroll
        for (int rg = 0; rg < 4; ++rg) {
            int row = wm * 32 + i * 16 + q * 4 + rg;
            #pragma unroll
            for (int j = 0; j < 4; ++j) {
                int col = wn * 64 + j * 16 + l16;
                float v = acc2[i][j][rg] + b2v[j];
                size_t gidx = (size_t)(row0 + row) * 128 + col;
                if (RES) v += h[gidx];
                h[gidx] = v;
                ov[i][j][rg] = v;
            }
        }
    }
    __syncthreads();                            // ssum free for reuse (all LN1 reads done)
    #pragma unroll
    for (int i = 0; i < 2; ++i) {
        #pragma unroll
        for (int rg = 0; rg < 4; ++rg) {
            float ps = 0.f, ps2 = 0.f;
            #pragma unroll
            for (int j = 0; j < 4; ++j) { float v = ov[i][j][rg]; ps += v; ps2 += v * v; }
            #pragma unroll
            for (int off = 1; off < 16; off <<= 1) {
                ps  += __shfl_xor(ps,  off, 16);
                ps2 += __shfl_xor(ps2, off, 16);
            }
            if (l16 == 0) {
                int row = wm * 32 + i * 16 + q * 4 + rg;
                ssum[row * 2 + wn] = ps; ssum2[row * 2 + wn] = ps2;
            }
        }
    }
    __syncthreads();                            // (4) final stats ready
    #pragma unroll
    for (int i = 0; i < 2; ++i) {
        #pragma unroll
        for (int rg = 0; rg < 4; ++rg) {
            int row = wm * 32 + i * 16 + q * 4 + rg;
            float S = ssum[row * 2 + 0] + ssum[row * 2 + 1];
            float S2 = ssum2[row * 2 + 0] + ssum2[row * 2 + 1];
            float mu = S * (1.0f / 128.0f);
            float var = S2 * (1.0f / 128.0f) - mu * mu;
            float rstd = rsqrtf(var + 1e-5f);
            #pragma unroll
            for (int j = 0; j < 4; ++j) {
                int col = wn * 64 + j * 16 + l16;
                float o = fmaxf((ov[i][j][rg] - mu) * rstd * bgv[j] + bbv[j], 0.f);
                xout[(size_t)(row0 + row) * 128 + col] = (_Float16)o;
            }
        }
    }
}

// ------------- mean pool over sorted batch (half input) -------------
__global__ __launch_bounds__(128) void pool_kernel(
    const _Float16* __restrict__ f, const int* __restrict__ batch, float* __restrict__ pooled)
{
    int g = blockIdx.x;
    int chunk = blockIdx.y;
    int c = threadIdx.x;
    int s = lower_bound_dev(batch, NN, g);
    int e = lower_bound_dev(batch, NN, g + 1);
    int len = e - s;
    if (len <= 0) return;
    int nch = gridDim.y;
    int per = (len + nch - 1) / nch;
    int cs = s + chunk * per;
    int ce = min(cs + per, e);
    if (cs >= ce) return;
    float acc = 0.f;
    for (int n = cs; n < ce; ++n) acc += (float)f[(size_t)n * HH + c];
    atomicAdd(&pooled[g * HH + c], acc);
}

// ------------- MLP head -------------
__global__ __launch_bounds__(128) void head_kernel(
    const float* __restrict__ pooled, const int* __restrict__ batch,
    const float* __restrict__ hw1, const float* __restrict__ hb1,
    const float* __restrict__ hw2, const float* __restrict__ hb2,
    const float* __restrict__ hw3, const float* __restrict__ hb3,
    float* __restrict__ out)
{
    __shared__ float p[HH];
    __shared__ float o1[64];
    __shared__ float o2[32];
    int g = blockIdx.x;
    int t = threadIdx.x;
    int s = lower_bound_dev(batch, NN, g);
    int e = lower_bound_dev(batch, NN, g + 1);
    float cnt = fmaxf((float)(e - s), 1.0f);
    p[t] = pooled[g * HH + t] / cnt;
    __syncthreads();
    if (t < 64) {
        float acc = hb1[t];
        for (int k = 0; k < HH; ++k) acc += p[k] * hw1[k * 64 + t];
        o1[t] = fmaxf(acc, 0.f);
    }
    __syncthreads();
    if (t < 32) {
        float acc = hb2[t];
        for (int k = 0; k < 64; ++k) acc += o1[k] * hw2[k * 32 + t];
        o2[t] = fmaxf(acc, 0.f);
    }
    __syncthreads();
    if (t == 0) {
        float acc = hb3[0];
        for (int k = 0; k < 32; ++k) acc += o2[k] * hw3[k];
        out[g] = acc;
    }
}

extern "C" void kernel_launch(void* const* d_in, const int* in_sizes, int n_in,
                              void* d_out, int out_size, void* d_ws, size_t ws_size,
                              hipStream_t stream)
{
    const float* x      = (const float*)d_in[0];
    const float* eattr  = (const float*)d_in[1];
    const float* node_w = (const float*)d_in[2];
    const float* node_b = (const float*)d_in[3];
    const float* edge_w = (const float*)d_in[4];
    const float* edge_b = (const float*)d_in[5];
    const float* tptr   = (const float*)d_in[6];
    const float* lin1_w = (const float*)d_in[7];
    const float* lin1_b = (const float*)d_in[8];
    const float* ln1_g  = (const float*)d_in[9];
    const float* ln1_bt = (const float*)d_in[10];
    const float* lin2_w = (const float*)d_in[11];
    const float* lin2_b = (const float*)d_in[12];
    const float* blk_g  = (const float*)d_in[13];
    const float* blk_b  = (const float*)d_in[14];
    const float* hw1    = (const float*)d_in[15];
    const float* hb1    = (const float*)d_in[16];
    const float* hw2    = (const float*)d_in[17];
    const float* hb2    = (const float*)d_in[18];
    const float* hw3    = (const float*)d_in[19];
    const float* hb3    = (const float*)d_in[20];
    const int*   eidx   = (const int*)d_in[21];
    const int*   batch  = (const int*)d_in[22];
    const int* src = eidx;
    const int* dst = eidx + NE;
    float* out = (float*)d_out;

    char* ws = (char*)d_ws;
    size_t off = 0;
    auto carve = [&](size_t bytes) -> char* {
        char* p = ws + off;
        off = (off + bytes + 255) & ~(size_t)255;
        return p;
    };
    float*    h      = (float*)carve((size_t)NN * HH * 4);
    _Float16* xh_in  = (_Float16*)carve((size_t)NX * 2);
    _Float16* xa     = (_Float16*)carve((size_t)NN * HH * 2);
    _Float16* xb     = (_Float16*)carve((size_t)NN * HH * 2);
    _Float16* oh     = (_Float16*)carve((size_t)NN * HH * 2);
    _Float16* rh     = (_Float16*)carve((size_t)NN * HH * 2);
    _Float16* nwt    = (_Float16*)carve((size_t)16384 * 2);
    _Float16* w1t    = (_Float16*)carve((size_t)98304 * 2);
    _Float16* w2t    = (_Float16*)carve((size_t)98304 * 2);
    int*      counts = (int*)carve((size_t)NN * 4);
    int*      rank   = (int*)carve((size_t)NE * 4);
    int*      tmp    = (int*)carve((size_t)NN * 4);
    int*      btot   = (int*)carve((size_t)64 * 4);
    int*      rowp   = (int*)carve((size_t)(NN + 1) * 4);
    int2*     rec    = (int2*)carve((size_t)NE * 8);
    float*    pooled = (float*)carve((size_t)NG * HH * 4);

    hipMemsetAsync(counts, 0, (size_t)NN * 4, stream);

    {   // convert + pooled-zero + count_rank
        int total = NX4 + 16384 + 98304 + 98304 + NG * HH + NE;
        convert_kernel<<<(total + 255) / 256, 256, 0, stream>>>(
            x, node_w, lin1_w, lin2_w, dst, counts, rank, pooled, xh_in, nwt, w1t, w2t);
    }
    const int NB = (NN + 1023) / 1024;   // 40
    scanA_kernel<<<NB, 1024, 0, stream>>>(counts, tmp, btot);
    scanC_kernel<<<NB, 1024, 0, stream>>>(tmp, btot, rowp);
    fill2_kernel<<<(NE + 255) / 256, 256, 0, stream>>>(src, dst, eattr, rowp, rank, rec);

    // node linear: xa = half(x @ node_w + node_b)
    gemm_mfma<<<dim3(1, NN / 64), 256, 0, stream>>>(xh_in, nwt, node_b, xa, NN, HH, DIM_IN);

    // layer 0: agg(xa) -> oh; MLP -> h, xb (post-LN uses blk[1])
    agg_kernel<<<NN / 4, 256, 0, stream>>>(xa, rowp, rec, edge_w, edge_b, tptr, 0, oh);
    mlp_fused<0><<<NN / 64, 256, 0, stream>>>(
        oh, w1t, lin1_b, ln1_g, ln1_bt, w2t, lin2_b,
        h, blk_g + 1 * HH, blk_b + 1 * HH, xb);
    // layer 1: agg(xb) -> oh; MLP (+res) -> h, xa (post-LN uses blk[2])
    agg_kernel<<<NN / 4, 256, 0, stream>>>(xb, rowp, rec, edge_w, edge_b, tptr, 1, oh);
    mlp_fused<1><<<NN / 64, 256, 0, stream>>>(
        oh, w1t + 32768, lin1_b + HH2, ln1_g + HH2, ln1_bt + HH2, w2t + 32768, lin2_b + HH,
        h, blk_g + 2 * HH, blk_b + 2 * HH, xa);
    // layer 2: agg(xa) -> oh; MLP (+res) -> h, rh (final LN uses blk[0])
    agg_kernel<<<NN / 4, 256, 0, stream>>>(xa, rowp, rec, edge_w, edge_b, tptr, 2, oh);
    mlp_fused<1><<<NN / 64, 256, 0, stream>>>(
        oh, w1t + 2 * 32768, lin1_b + 2 * HH2, ln1_g + 2 * HH2, ln1_bt + 2 * HH2,
        w2t + 2 * 32768, lin2_b + 2 * HH,
        h, blk_g, blk_b, rh);

    pool_kernel<<<dim3(NG, 8), 128, 0, stream>>>(rh, batch, pooled);
    head_kernel<<<NG, 128, 0, stream>>>(pooled, batch, hw1, hb1, hw2, hb2, hw3, hb3, out);
}